// Round 3
// baseline (1034.998 us; speedup 1.0000x reference)
//
#include <hip/hip_runtime.h>
#include <math.h>

// Problem constants
#define BQ   4
#define GQ   8
#define NHQ  8
#define SQ   4096

// ---------------------------------------------------------------------------
// Memory plan (ws_size >= 512 MiB; round-2 verified):
//   d_ws: q      fp32 [bg][c][4096]   134,217,728 B   (dead after attn2 ->
//                                      head reused for Wpred hi/lo planes)
//         kb     fp32 [bg][c][4096]   134,217,728 B
//         vb     fp32 [bg][c][4096]   134,217,728 B
//         og_h   bf16 [bg][t][c]       67,108,864 B
//         og_l   bf16 [bg][t][c]       67,108,864 B
//   d_out pred region: xt_h/xt_l bf16 [bg][t][c] (dead after qkv gemm)
//   d_out aout region: Wqkv hi/lo planes (dead once attn2 writes aout)
// Sequence: convert_x -> convert_wqkv -> qkv gemm -> attn2 -> convert_wpred
//           -> pred gemm.
// k[row][t+1] at t=4095 reads the next row's t=0 (valid memory) and is
// corrected by an in-kernel fix-up using b_qkv (pad column = bias).
// ---------------------------------------------------------------------------

typedef __attribute__((ext_vector_type(8))) short short8;
typedef __attribute__((ext_vector_type(4))) float f32x4;

__device__ __forceinline__ unsigned short f2b(float f) {
    unsigned int u = __float_as_uint(f);
    unsigned int r = u + 0x7fffu + ((u >> 16) & 1u);   // RNE
    return (unsigned short)(r >> 16);
}
__device__ __forceinline__ float b2f(unsigned short h) {
    return __uint_as_float(((unsigned int)h) << 16);
}
__device__ __forceinline__ void gll16(const void* g, void* l) {
    __builtin_amdgcn_global_load_lds((const __attribute__((address_space(1))) void*)g,
                                     (__attribute__((address_space(3))) void*)l, 16, 0, 0);
}

// ---------------------------------------------------------------------------
// Transpose+convert: x fp32 [bg][c][t] -> xt_h/xt_l bf16 [bg][t][c]
// ---------------------------------------------------------------------------
__global__ __launch_bounds__(256) void convert_x_k(const float* __restrict__ x,
    unsigned short* __restrict__ xhi, unsigned short* __restrict__ xlo)
{
    __shared__ float lds[64 * 65];
    const int tid = threadIdx.x;
    const int t0 = blockIdx.x << 6;
    const int c0 = blockIdx.y << 6;
    const int bg = blockIdx.z;
    const int hi16 = tid >> 4, lo16 = tid & 15;
    const float* xb = x + ((size_t)bg << 8) * SQ;
#pragma unroll
    for (int p = 0; p < 4; ++p) {
        int c = (p << 4) + hi16;
        const float4 v4 = *(const float4*)(xb + (size_t)(c0 + c) * SQ + t0 + (lo16 << 2));
        lds[((lo16 << 2) + 0) * 65 + c] = v4.x;
        lds[((lo16 << 2) + 1) * 65 + c] = v4.y;
        lds[((lo16 << 2) + 2) * 65 + c] = v4.z;
        lds[((lo16 << 2) + 3) * 65 + c] = v4.w;
    }
    __syncthreads();
#pragma unroll
    for (int p = 0; p < 4; ++p) {
        int t = (p << 4) + hi16;
        float f0 = lds[t * 65 + (lo16 << 2) + 0];
        float f1 = lds[t * 65 + (lo16 << 2) + 1];
        float f2 = lds[t * 65 + (lo16 << 2) + 2];
        float f3 = lds[t * 65 + (lo16 << 2) + 3];
        ushort4 h, l;
        h.x = f2b(f0); l.x = f2b(f0 - b2f(h.x));
        h.y = f2b(f1); l.y = f2b(f1 - b2f(h.y));
        h.z = f2b(f2); l.z = f2b(f2 - b2f(h.z));
        h.w = f2b(f3); l.w = f2b(f3 - b2f(h.w));
        size_t o = (((size_t)bg * SQ + t0 + t) << 8) + c0 + (lo16 << 2);
        *(ushort4*)(xhi + o) = h;
        *(ushort4*)(xlo + o) = l;
    }
}

// ---------------------------------------------------------------------------
// Split fp32 weights into bf16 hi/lo planes (one-shot, tiny).
// ---------------------------------------------------------------------------
__global__ __launch_bounds__(256) void convert_w_k(const float* __restrict__ W,
    unsigned short* __restrict__ Wh, unsigned short* __restrict__ Wl, int n4)
{
    int i = blockIdx.x * 256 + threadIdx.x;
    if (i >= n4) return;
    const float4 w4 = ((const float4*)W)[i];
    ushort4 h, l;
    h.x = f2b(w4.x); l.x = f2b(w4.x - b2f(h.x));
    h.y = f2b(w4.y); l.y = f2b(w4.y - b2f(h.y));
    h.z = f2b(w4.z); l.z = f2b(w4.z - b2f(h.z));
    h.w = f2b(w4.w); l.w = f2b(w4.w - b2f(h.w));
    ((ushort4*)Wh)[i] = h;
    ((ushort4*)Wl)[i] = l;
}

// ---------------------------------------------------------------------------
// Split-bf16 MFMA GEMM with pre-split A/B planes, all staged via
// global_load_lds(16B) + inverse-swizzled source. 128x128 tile, BK=32,
// 4 waves, 48 MFMA per K-step (hh, hl, lh). XCD-bijective block swizzle.
// ---------------------------------------------------------------------------
template <int M, bool QKV>
__global__ __launch_bounds__(256) void gemm3_k(
    const unsigned short* __restrict__ Ah, const unsigned short* __restrict__ Al,
    const unsigned short* __restrict__ Bh, const unsigned short* __restrict__ Bl,
    const float* __restrict__ bias,
    float* __restrict__ o0p, float* __restrict__ o1p, float* __restrict__ o2p)
{
    constexpr int NO = M / 128;
    __shared__ __align__(16) char smem[32768];
    const int AHI = 0, ALO = 8192, BHI = 16384, BLO = 24576;
    const int tid = threadIdx.x;
    const int lane = tid & 63, wid = tid >> 6;
    const int wm = wid >> 1, wn = wid & 1;

    // XCD swizzle: consecutive work-ids share (bg,t0); each XCD gets a run.
    const int nblk = gridDim.x;
    const int lin = blockIdx.x;
    const int L = (lin & 7) * (nblk >> 3) + (lin >> 3);
    const int oi = L % NO;
    const int r = L / NO;
    const int t_idx = r & 31, bg = r >> 5;
    const int o0 = oi << 7, t0 = t_idx << 7;
    const int g = bg & 7;

    const size_t abase = (size_t)g * M * 256;
    const size_t bbase = (((size_t)bg << 12) + (size_t)t0) << 8;

    f32x4 acc[4][4];
    const f32x4 zero = {0.f, 0.f, 0.f, 0.f};
#pragma unroll
    for (int i = 0; i < 4; ++i)
#pragma unroll
        for (int j = 0; j < 4; ++j) acc[i][j] = zero;

    for (int k0 = 0; k0 < 256; k0 += 32) {
#pragma unroll
        for (int s = 0; s < 2; ++s) {
            int w = tid + (s << 8);                 // 0..511 16B chunks
            int row = w >> 2;
            int j = (w & 3) ^ ((w >> 3) & 3);       // inverse of LDS swizzle
            size_t ga = abase + (size_t)(o0 + row) * 256 + k0 + (j << 3);
            size_t gb = bbase + ((size_t)row << 8) + k0 + (j << 3);
            gll16(Ah + ga, smem + AHI + (w << 4));
            gll16(Al + ga, smem + ALO + (w << 4));
            gll16(Bh + gb, smem + BHI + (w << 4));
            gll16(Bl + gb, smem + BLO + (w << 4));
        }
        __syncthreads();

        short8 ah[4], al[4], bh[4], bl[4];
        const int lr = lane & 15, kc = lane >> 4;
#pragma unroll
        for (int mi = 0; mi < 4; ++mi) {
            int row = (wm << 6) + (mi << 4) + lr;
            int off = (row << 6) + ((kc ^ ((row >> 1) & 3)) << 4);
            ah[mi] = *(const short8*)(smem + AHI + off);
            al[mi] = *(const short8*)(smem + ALO + off);
        }
#pragma unroll
        for (int ni = 0; ni < 4; ++ni) {
            int row = (wn << 6) + (ni << 4) + lr;
            int off = (row << 6) + ((kc ^ ((row >> 1) & 3)) << 4);
            bh[ni] = *(const short8*)(smem + BHI + off);
            bl[ni] = *(const short8*)(smem + BLO + off);
        }
#pragma unroll
        for (int mi = 0; mi < 4; ++mi)
#pragma unroll
            for (int ni = 0; ni < 4; ++ni)
                acc[mi][ni] = __builtin_amdgcn_mfma_f32_16x16x32_bf16(ah[mi], bh[ni], acc[mi][ni], 0, 0, 0);
#pragma unroll
        for (int mi = 0; mi < 4; ++mi)
#pragma unroll
            for (int ni = 0; ni < 4; ++ni)
                acc[mi][ni] = __builtin_amdgcn_mfma_f32_16x16x32_bf16(ah[mi], bl[ni], acc[mi][ni], 0, 0, 0);
#pragma unroll
        for (int mi = 0; mi < 4; ++mi)
#pragma unroll
            for (int ni = 0; ni < 4; ++ni)
                acc[mi][ni] = __builtin_amdgcn_mfma_f32_16x16x32_bf16(al[mi], bh[ni], acc[mi][ni], 0, 0, 0);
        __syncthreads();
    }

    // ---- epilogue: C layout col=lane&15 (t), row=(lane>>4)*4+r (o)
    const int lr = lane & 15, lq = lane >> 4;
#pragma unroll
    for (int mi = 0; mi < 4; ++mi) {
#pragma unroll
        for (int r2 = 0; r2 < 4; ++r2) {
            const int row = o0 + (wm << 6) + (mi << 4) + (lq << 2) + r2;
            const float bo = bias[g * M + row];
            float* rowbase;
            if (QKV) {
                const int j = row % 3, c = row / 3;
                float* bp = (j == 0) ? o0p : ((j == 1) ? o1p : o2p);
                rowbase = bp + (((size_t)bg * 256 + c) << 12);
            } else {
                rowbase = o0p + (((size_t)(bg >> 3) * 2048 + g * 256 + row) << 12);
            }
#pragma unroll
            for (int ni = 0; ni < 4; ++ni) {
                const int t = t0 + (wn << 6) + (ni << 4) + lr;
                rowbase[t] = acc[mi][ni][r2] + bo;
            }
        }
    }
}

// ---------------------------------------------------------------------------
// Attention, lane = t: block = (b, g, t0 of 64), 512 threads (wave = n).
// All q/k/v reads coalesced global (uniform base + t). Scores, sigmoid,
// normalize, PV fully in registers. og transposed through a 64 KB
// XOR-swizzled LDS tile -> coalesced [bg][t][c] bf16 hi/lo stores.
// ---------------------------------------------------------------------------
__global__ __launch_bounds__(512) void attn2_k(
    const float* __restrict__ q, const float* __restrict__ kb, const float* __restrict__ vb,
    const float* __restrict__ bqkv,
    unsigned short* __restrict__ og_h, unsigned short* __restrict__ og_l,
    float* __restrict__ aout)
{
    __shared__ unsigned int ogt[64 * 256];        // 64 KB, XOR-swizzled cols

    const int nblk = gridDim.x;                   // 2048
    const int lin = blockIdx.x;
    const int L = (lin & 7) * (nblk >> 3) + (lin >> 3);
    const int g = L & 7;
    const int tt = (L >> 3) & 63;
    const int b = L >> 9;
    const int t0 = tt << 6;
    const int n = threadIdx.x >> 6;
    const int tl = (int)threadIdx.x & 63;
    const int t = t0 + tl;
    const bool lastblk = (t0 == SQ - 64);

    const int b8 = b << 3;
    const float* qrow = q + (((size_t)((b8 + g) << 8) + (n << 5)) << 12);
    const float* krow = kb + (((size_t)(b8 << 8) + (n << 5)) << 12);
    const float* vrow = vb + (((size_t)(b8 << 8) + (n << 5)) << 12);

    // ---- scores ----
    float s[16];
#pragma unroll
    for (int e = 0; e < 16; ++e) s[e] = 0.f;

#pragma unroll 4
    for (int d = 0; d < 32; ++d) {
        const float qv = qrow[((size_t)d << 12) + t];
#pragma unroll
        for (int e8 = 0; e8 < 8; ++e8) {
            const float* kr = krow + ((size_t)((e8 << 8) + d) << 12);
            s[e8]     += qv * kr[t];
            s[8 + e8] += qv * kr[t + 1];
        }
    }
    if (lastblk) {                 // fix t+1 pad column (k pad = bias only)
        if (t == SQ - 1) {
#pragma unroll
            for (int e8 = 0; e8 < 8; ++e8) s[8 + e8] = 0.f;
            for (int d = 0; d < 32; ++d) {
                const float qv = qrow[((size_t)d << 12) + t];
#pragma unroll
                for (int e8 = 0; e8 < 8; ++e8)
                    s[8 + e8] += qv * bqkv[e8 * 768 + ((n << 5) + d) * 3 + 1];
            }
        }
    }

    // ---- sigmoid + normalize ----
    float zs = 0.f;
#pragma unroll
    for (int e = 0; e < 16; ++e) {
        const float z = 1.f / (1.f + __expf(-s[e] * 0.17677669529663687f));
        s[e] = z; zs += z;
    }
    const float inv = 1.f / (1e-9f + zs);
#pragma unroll
    for (int e = 0; e < 16; ++e) s[e] *= inv;

    // ---- attn_out: [b][n][g][e][t], t-coalesced ----
    {
        const size_t abase = ((size_t)(((b * NHQ + n) * GQ + g) << 4) << 12) + t;
#pragma unroll
        for (int e = 0; e < 16; ++e)
            aout[abase + ((size_t)e << 12)] = s[e];
    }

    // ---- PV -> og tile in LDS ----
    for (int d = 0; d < 32; ++d) {
        float v0k[8];
        float acc = 0.f;
#pragma unroll
        for (int e8 = 0; e8 < 8; ++e8) {
            const float* vr = vrow + ((size_t)((e8 << 8) + d) << 12);
            const float v0 = vr[t];
            const float v1 = vr[t + 1];
            v0k[e8] = v0;
            acc += s[e8] * v0 + s[8 + e8] * v1;
        }
        if (lastblk) {
            if (t == SQ - 1) {
                acc = 0.f;
#pragma unroll
                for (int e8 = 0; e8 < 8; ++e8)
                    acc += s[e8] * v0k[e8] + s[8 + e8] * bqkv[e8 * 768 + ((n << 5) + d) * 3 + 2];
            }
        }
        const unsigned short hh = f2b(acc);
        const unsigned short ll = f2b(acc - b2f(hh));
        const int c = (n << 5) + d;
        ogt[(tl << 8) + (c ^ (tl & 31))] = ((unsigned)hh << 16) | (unsigned)ll;
    }
    __syncthreads();

    // ---- write out og hi/lo planes, [bg][t][c] row-coalesced ----
    const size_t rb = ((size_t)(b8 + g) << 12) + t0;
#pragma unroll
    for (int it = 0; it < 16; ++it) {
        const int qq = (int)threadIdx.x + (it << 9);   // 0..8191
        const int trow = qq >> 7;
        const int cp = (qq & 127) << 1;
        const unsigned u0 = ogt[(trow << 8) + (cp ^ (trow & 31))];
        const unsigned u1 = ogt[(trow << 8) + ((cp + 1) ^ (trow & 31))];
        const size_t off = ((rb + trow) << 8) + cp;
        ushort2 hv, lv;
        hv.x = (unsigned short)(u0 >> 16); hv.y = (unsigned short)(u1 >> 16);
        lv.x = (unsigned short)(u0 & 0xffffu); lv.y = (unsigned short)(u1 & 0xffffu);
        *(ushort2*)(og_h + off) = hv;
        *(ushort2*)(og_l + off) = lv;
    }
}

// ---------------------------------------------------------------------------
extern "C" void kernel_launch(void* const* d_in, const int* in_sizes, int n_in,
                              void* d_out, int out_size, void* d_ws, size_t ws_size,
                              hipStream_t stream)
{
    const float* x      = (const float*)d_in[0];
    const float* w_qkv  = (const float*)d_in[1];
    const float* b_qkv  = (const float*)d_in[2];
    const float* w_pred = (const float*)d_in[3];
    const float* b_pred = (const float*)d_in[4];

    float* pred = (float*)d_out;                             // 33,554,432 f
    float* aout = pred + (size_t)33554432;                   // 16,777,216 f

    unsigned short* xt_h = (unsigned short*)d_out;           // pred region scratch
    unsigned short* xt_l = xt_h + (size_t)33554432;
    unsigned short* Wq_h = (unsigned short*)aout;            // aout region scratch
    unsigned short* Wq_l = Wq_h + (size_t)1572864;

    float* q  = (float*)d_ws;
    float* kb = q + (size_t)33554432;
    float* vb = kb + (size_t)33554432;
    unsigned short* og_h = (unsigned short*)(vb + (size_t)33554432);
    unsigned short* og_l = og_h + (size_t)33554432;
    unsigned short* Wp_h = (unsigned short*)d_ws;            // q region, post-attn
    unsigned short* Wp_l = Wp_h + (size_t)524288;

    // 1) x -> bf16 hi/lo transposed [bg][t][c]
    convert_x_k<<<dim3(64, 4, 32), 256, 0, stream>>>(x, xt_h, xt_l);
    // 2) w_qkv -> hi/lo planes (parked in aout region)
    convert_w_k<<<1536, 256, 0, stream>>>(w_qkv, Wq_h, Wq_l, 393216);
    // 3) QKV projection -> q/kb/vb fp32 [bg][c][t]
    gemm3_k<768, true><<<6144, 256, 0, stream>>>(Wq_h, Wq_l, xt_h, xt_l, b_qkv, q, kb, vb);
    // 4) attention -> aout + og hi/lo planes
    attn2_k<<<2048, 512, 0, stream>>>(q, kb, vb, b_qkv, og_h, og_l, aout);
    // 5) w_pred -> hi/lo planes (parked in dead q region)
    convert_w_k<<<512, 256, 0, stream>>>(w_pred, Wp_h, Wp_l, 131072);
    // 6) pred projection -> pred
    gemm3_k<256, false><<<2048, 256, 0, stream>>>(Wp_h, Wp_l, og_h, og_l, b_pred, pred, nullptr, nullptr);
}